// Round 1
// baseline (854.228 us; speedup 1.0000x reference)
//
#include <hip/hip_runtime.h>
#include <math.h>

// Masked similar-user attention: out[b,s,d] = softmax_u(mask? -1e9 : cu[b]·sue[b,s,u]) · sue[b,s,u,d] + cie[b,s,d]
// One wave (64 lanes) per (b,s) tile; each wave processes 8 tiles with a
// double-buffered register pipeline: loads for tile t+4 (sue/mask/cu) are in
// flight while tile t is computed, so the memory pipe is never idle during the
// long cross-lane shuffle chains (dot reduce, softmax reduce, output reduce).
// Lane layout: lane l, chunk j holds float4 at tile element j*256+4l
//   => u = 8j + (l>>3), d = 4*(l&7). j=0..6 covers u in [0,56); u>=50 padded (-inf).

#define NEG_INF_F (-1e9f)

constexpr int B = 512, S = 200, U = 50, D = 32;
constexpr int TILES = B * S;                      // 102400
constexpr int TILE_F4 = U * D / 4;                // 400 float4 per tile
constexpr int SUE_F4 = TILES * TILE_F4;           // 40,960,000 float4 total
constexpr int TPB = 256;                          // 4 waves / block
constexpr int TPW = 8;                            // tiles per wave
constexpr int TILES_PER_BLOCK = 4 * TPW;          // 32
constexpr int NBLK = TILES / TILES_PER_BLOCK;     // 3200 blocks (12.5/CU)

struct Tile {
    float4 v[7];   // sue fragments (28 VGPR)
    int    m[7];   // mask values for u = 8j+g
    float4 c;      // cu fragment for this tile's b
};

__device__ __forceinline__ void issue_tile(int tile, int lane, int g, int d0,
    const float4* __restrict__ sue4, const int* __restrict__ mask,
    const float* __restrict__ cu, Tile& T)
{
    const int base4 = tile * TILE_F4;
    // coalesced 1 KiB/wave loads; only j=6 can over-read (last tile) -> clamp just that one
    #pragma unroll
    for (int j = 0; j < 6; ++j) T.v[j] = sue4[base4 + j * 64 + lane];
    T.v[6] = sue4[min(base4 + 6 * 64 + lane, SUE_F4 - 1)];

    const int mrow = tile * U;
    #pragma unroll
    for (int j = 0; j < 6; ++j) T.m[j] = mask[mrow + j * 8 + g];   // u = 8j+g <= 47, in range
    T.m[6] = mask[mrow + min(48 + g, U - 1)];                      // u = 48+g, clamp pad lanes

    const int b = tile / S;
    T.c = *(const float4*)(cu + b * D + d0);
}

__device__ __forceinline__ void compute_tile(int tile, int lane, int g, int d0,
    const Tile& T, const float* __restrict__ cie, float* __restrict__ out)
{
    // residual load issued first; consumed ~40 instructions later (hidden)
    const float4 ci = *(const float4*)(cie + tile * D + d0);

    // ---- scores: per-lane partial dot, reduce over d via xor 1/2/4 ----
    float sc[7];
    #pragma unroll
    for (int j = 0; j < 7; ++j) {
        float p = T.v[j].x * T.c.x + T.v[j].y * T.c.y + T.v[j].z * T.c.z + T.v[j].w * T.c.w;
        p += __shfl_xor(p, 1);
        p += __shfl_xor(p, 2);
        p += __shfl_xor(p, 4);
        sc[j] = p;
    }

    // ---- mask (reference uses finite -1e9; padding u>=50 uses true -inf) ----
    #pragma unroll
    for (int j = 0; j < 6; ++j) if (T.m[j]) sc[j] = NEG_INF_F;
    {
        const int u = 48 + g;
        sc[6] = (u < U) ? (T.m[6] ? NEG_INF_F : sc[6]) : -INFINITY;
    }

    // ---- softmax over u: reduce across the 8 u-subgroups via xor 8/16/32 ----
    float mx = sc[0];
    #pragma unroll
    for (int j = 1; j < 7; ++j) mx = fmaxf(mx, sc[j]);
    mx = fmaxf(mx, __shfl_xor(mx, 8));
    mx = fmaxf(mx, __shfl_xor(mx, 16));
    mx = fmaxf(mx, __shfl_xor(mx, 32));

    float e[7];
    float ts = 0.f;
    #pragma unroll
    for (int j = 0; j < 7; ++j) {
        e[j] = __expf(sc[j] - mx);                // -inf -> 0; all-masked row -> uniform 1/50
        ts += e[j];
    }
    ts += __shfl_xor(ts, 8);
    ts += __shfl_xor(ts, 16);
    ts += __shfl_xor(ts, 32);

    // ---- weighted sum over u; normalization deferred to after the reduce ----
    float4 o = make_float4(0.f, 0.f, 0.f, 0.f);
    #pragma unroll
    for (int j = 0; j < 7; ++j) {
        o.x += e[j] * T.v[j].x; o.y += e[j] * T.v[j].y;
        o.z += e[j] * T.v[j].z; o.w += e[j] * T.v[j].w;
    }
    #pragma unroll
    for (int k = 8; k <= 32; k <<= 1) {
        o.x += __shfl_xor(o.x, k);
        o.y += __shfl_xor(o.y, k);
        o.z += __shfl_xor(o.z, k);
        o.w += __shfl_xor(o.w, k);
    }

    // ---- residual + store (lanes 0..7 write 128B contiguous) ----
    if (g == 0) {
        const float inv = 1.0f / ts;
        float4 r = make_float4(o.x * inv + ci.x, o.y * inv + ci.y,
                               o.z * inv + ci.z, o.w * inv + ci.w);
        *(float4*)(out + tile * D + d0) = r;
    }
}

__global__ __launch_bounds__(TPB) void DIB_69861938037647_kernel(
    const float* __restrict__ cu,    // [B, D]
    const float* __restrict__ sue,   // [B, S, U, D]
    const float* __restrict__ cie,   // [B, S, D]
    const int*   __restrict__ mask,  // [B, S, U]  nonzero = masked out
    float* __restrict__ out)         // [B, S, D]
{
    const int lane = threadIdx.x & 63;
    const int wave = threadIdx.x >> 6;
    const int g  = lane >> 3;                     // u subgroup 0..7
    const int d0 = (lane & 7) * 4;                // d offset 0,4,...,28
    const float4* sue4 = (const float4*)sue;

    int t = blockIdx.x * TILES_PER_BLOCK + wave;  // waves stride 4 tiles within block

    Tile A, Bf;
    issue_tile(t, lane, g, d0, sue4, mask, cu, A);

    #pragma unroll 1
    for (int k = 0; k < TPW / 2; ++k) {
        issue_tile(t + 4, lane, g, d0, sue4, mask, cu, Bf);   // prefetch t+4 into B
        compute_tile(t, lane, g, d0, A, cie, out);            // compute t from A
        if (k < TPW / 2 - 1)
            issue_tile(t + 8, lane, g, d0, sue4, mask, cu, A); // prefetch t+8 into A
        compute_tile(t + 4, lane, g, d0, Bf, cie, out);       // compute t+4 from B
        t += 8;
    }
}

extern "C" void kernel_launch(void* const* d_in, const int* in_sizes, int n_in,
                              void* d_out, int out_size, void* d_ws, size_t ws_size,
                              hipStream_t stream) {
    const float* cu   = (const float*)d_in[0];
    const float* sue  = (const float*)d_in[1];
    const float* cie  = (const float*)d_in[2];
    const int*   mask = (const int*)d_in[3];
    float* out = (float*)d_out;

    DIB_69861938037647_kernel<<<NBLK, TPB, 0, stream>>>(cu, sue, cie, mask, out);
}